// Round 12
// baseline (292.915 us; speedup 1.0000x reference)
//
#include <hip/hip_runtime.h>

typedef __bf16 bf16x8 __attribute__((ext_vector_type(8)));
typedef float f32x4 __attribute__((ext_vector_type(4)));
typedef unsigned short u16;
typedef unsigned int u32;
typedef unsigned long long u64;

__device__ __forceinline__ u16 f2b(float f) {
  return __builtin_bit_cast(u16, (__bf16)f);
}
__device__ __forceinline__ float b2f_lo(u32 pk) {
  return __builtin_bit_cast(float, pk << 16);
}
__device__ __forceinline__ float b2f_hi(u32 pk) {
  return __builtin_bit_cast(float, pk & 0xffff0000u);
}
__device__ __forceinline__ float leaky(float x) { return x > 0.f ? x : 0.1f * x; }
__device__ __forceinline__ f32x4 mfma16(bf16x8 a, bf16x8 b, f32x4 c) {
  return __builtin_amdgcn_mfma_f32_16x16x32_bf16(a, b, c, 0, 0, 0);
}

// LDS row paddings: 64->72, 128->136 u16 (stride%32 dwords = 4 -> 2-way, free)
#define P64 72
#define P128 136
// fixed-stride CSR record, 128B (2 cache lines), 32 ints:
//   int[0]=cnt  int[1]=pspill(float, spill-only possum)
//   int[2+j] = slot j = (src<<12) | fix12(bitpos)   (src < 2^20, 12-bit pos)
#define CAP 16
#define RSTRIDE 32  // ints

// ================= k_prep: weight transposes + mbits + header zeroing ========
__global__ __launch_bounds__(256) void k_prep(
    const float* nm_w1, const float* ng_w1, const float* nm_w2, const float* ng_w2,
    const float* o_w1, const float* o_b1, const float* g_w2, const float* g_b2,
    const float* pi_w2, const float* pi_b2, const int* is_module,
    u16* wt_yc, float* bias_y, u16* wt_f1m, u16* wt_f1g, float* w_pos,
    u16* wt2m, u16* wt2g, u16* wt_oh, u16* gt, float* bp, u32* mbits,
    int* rec, int* spillcnt, int N) {
  int i = blockIdx.x * 256 + threadIdx.x;
  if (i < 9216) {
    int ty = i / 4608, rem = i % 4608, n = rem / P64, k = rem % P64;
    float v = 0.f;
    if (k < 64) {
      const float* w1 = ty ? ng_w1 : nm_w1;
      for (int t = 0; t < 128; t++) v += pi_w2[k * 128 + t] * w1[t * 64 + n];
    }
    wt_yc[i] = f2b(v);
    return;
  }
  i -= 9216;
  if (i < 128) {
    int ty = i >> 6, n = i & 63;
    const float* w1 = ty ? ng_w1 : nm_w1;
    float v = 0.f;
    for (int t = 0; t < 128; t++) v += pi_b2[t] * w1[t * 64 + n];
    bias_y[i] = v;
    return;
  }
  i -= 128;
  if (i < 4608) {
    int n = i / P64, k = i % P64;
    wt_f1m[i] = f2b(k < 64 ? nm_w1[(129 + k) * 64 + n] : 0.f);
    return;
  }
  i -= 4608;
  if (i < 4608) {
    int n = i / P64, k = i % P64;
    wt_f1g[i] = f2b(k < 64 ? ng_w1[(128 + k) * 64 + n] : 0.f);
    return;
  }
  i -= 4608;
  if (i < 64) { w_pos[i] = nm_w1[128 * 64 + i]; return; }
  i -= 64;
  if (i < 9216) {
    int n = i / P64, k = i % P64;
    wt2m[i] = f2b(k < 64 ? nm_w2[k * 128 + n] : 0.f);
    return;
  }
  i -= 9216;
  if (i < 9216) {
    int n = i / P64, k = i % P64;
    wt2g[i] = f2b(k < 64 ? ng_w2[k * 128 + n] : 0.f);
    return;
  }
  i -= 9216;
  if (i < 17408) {
    int n = i / P128, k = i % P128;
    wt_oh[i] = f2b(k < 128 ? o_w1[k * 128 + n] : 0.f);
    return;
  }
  i -= 17408;
  if (i < 9216) {
    int n = i / P64, k = i % P64;
    float v = 0.f;
    if (k < 64)
      for (int t = 0; t < 128; t++) v += g_w2[k * 128 + t] * o_w1[(128 + t) * 128 + n];
    gt[i] = f2b(v);
    return;
  }
  i -= 9216;
  if (i < 128) {
    float s = o_b1[i];
    for (int t = 0; t < 128; t++) s += g_b2[t] * o_w1[(128 + t) * 128 + i];
    bp[i] = s;
    return;
  }
  i -= 128;
  // mbits ballot + record header zeroing (wave-aligned: 63808 % 64 == 0)
  {
    int n = i;
    int lane = threadIdx.x & 63;
    bool v = (n < N) && (is_module[n] == 1);
    u64 b = __ballot(v);
    if (lane == 0 && n < N) mbits[n >> 5] = (u32)b;
    if (lane == 32 && n < N) mbits[n >> 5] = (u32)(b >> 32);
    if (n < N) *(u64*)&rec[(size_t)n * RSTRIDE] = 0;  // cnt + pspill
    if (n == 0) *spillcnt = 0;
  }
}

// ================= k_scatter: flat edge pass, nt loads + nt slot stores ======
__global__ void k_scatter(const int* src_m, const int* dst_m, const int* src_g,
                          const int* dst_g, const u32* mbits, const float* bitpos,
                          int* rec, u64* spill, int* spillcnt, int E) {
  int e = blockIdx.x * 256 + threadIdx.x;
  if (e < E) {
    int d = __builtin_nontemporal_load(&dst_m[e]);
    if ((mbits[d >> 5] >> (d & 31)) & 1) {
      int c = atomicAdd(&rec[d * RSTRIDE], 1);
      int s = __builtin_nontemporal_load(&src_m[e]);
      float bpv = __builtin_nontemporal_load(&bitpos[e]);
      if (c < CAP) {
        int bp12 = (int)(bpv * 4096.f);
        if (bp12 > 4095) bp12 = 4095;
        __builtin_nontemporal_store((s << 12) | bp12,
                                    &rec[(size_t)d * RSTRIDE + 2 + c]);
      } else {
        int p = atomicAdd(spillcnt, 1);
        spill[p] = ((u64)(u32)d << 32) | (u32)s;
        atomicAdd((float*)&rec[d * RSTRIDE + 1], bpv);
      }
    }
  } else if (e < 2 * E) {
    int d = __builtin_nontemporal_load(&dst_g[e - E]);
    if (!((mbits[d >> 5] >> (d & 31)) & 1)) {
      int c = atomicAdd(&rec[d * RSTRIDE], 1);
      int s = __builtin_nontemporal_load(&src_g[e - E]);
      if (c < CAP) {
        __builtin_nontemporal_store(s << 12, &rec[(size_t)d * RSTRIDE + 2 + c]);
      } else {
        int p = atomicAdd(spillcnt, 1);
        spill[p] = ((u64)(u32)d << 32) | (u32)s;
      }
    }
  }
}

// ================= k_pre (persistent): layer1(pi) -> y0 ; f1 =================
__global__ __launch_bounds__(512) void k_pre(const float* pf, const float* feat,
                                             const float* pi_w1, const float* pi_b1,
                                             const u16* wt_yc_g, const float* bias_y,
                                             const u16* wt_f1m_g, const u16* wt_f1g_g,
                                             const float* nm_b1, const float* ng_b1,
                                             const u32* mbits,
                                             u16* y0, u16* f1, int N) {
  __shared__ __align__(16) u16 wyc[2][64 * P64];
  __shared__ __align__(16) u16 wf[2][64 * P64];
  __shared__ __align__(16) u16 tbuf[8][16 * P64];
  for (int i = threadIdx.x; i < 2304; i += 512) {
    ((u32*)wyc[0])[i] = ((const u32*)wt_yc_g)[i];
    ((u32*)wyc[1])[i] = ((const u32*)wt_yc_g)[2304 + i];
    ((u32*)wf[0])[i] = ((const u32*)wt_f1m_g)[i];
    ((u32*)wf[1])[i] = ((const u32*)wt_f1g_g)[i];
  }

  int lane = threadIdx.x & 63, wv = threadIdx.x >> 6;
  int lid = lane & 15, q = lane >> 4;

  bf16x8 w1f[4];
#pragma unroll
  for (int nt = 0; nt < 4; nt++) {
    bf16x8 f;
#pragma unroll
    for (int j = 0; j < 8; j++) {
      int k = q * 8 + j;
      f[j] = (__bf16)((k < 4) ? pi_w1[k * 64 + nt * 16 + lid] : 0.f);
    }
    w1f[nt] = f;
  }
  __syncthreads();  // weight LDS ready

  int nbat = (N + 15) >> 4;
  for (int b0 = blockIdx.x * 8; b0 < nbat; b0 += gridDim.x * 8) {
    int b = b0 + wv;
    int batch = b < nbat ? b : nbat - 1;
    int id = batch * 16 + lid;
    if (id >= N) id = N - 1;

    // ---- pi layer 1: 4 -> 64, leaky -> tbuf (A-layout transpose)
    bf16x8 a;
#pragma unroll
    for (int j = 0; j < 8; j++)
      a[j] = (__bf16)((q == 0 && j < 4) ? pf[(size_t)id * 4 + j] : 0.f);
    f32x4 z1[4];
#pragma unroll
    for (int nt = 0; nt < 4; nt++) {
      f32x4 c = {0.f, 0.f, 0.f, 0.f};
      z1[nt] = mfma16(a, w1f[nt], c);
    }
    __syncthreads();
#pragma unroll
    for (int nt = 0; nt < 4; nt++) {
      float bb = pi_b1[nt * 16 + lid];
#pragma unroll
      for (int r = 0; r < 4; r++)
        tbuf[wv][(q * 4 + r) * P64 + nt * 16 + lid] = f2b(leaky(z1[nt][r] + bb));
    }
    __syncthreads();
    bf16x8 a20 = *(const bf16x8*)&tbuf[wv][lid * P64 + q * 8];
    bf16x8 a21 = *(const bf16x8*)&tbuf[wv][lid * P64 + 32 + q * 8];

    int idr_[4];
#pragma unroll
    for (int r = 0; r < 4; r++) {
      int ii = batch * 16 + q * 4 + r;
      idr_[r] = ii < N ? ii : N - 1;
    }

    // ---- y0[ty] = a2 @ Wcomb_ty + bias_y_ty (64 -> 64 per type)
#pragma unroll
    for (int ty = 0; ty < 2; ty++) {
#pragma unroll
      for (int nt = 0; nt < 4; nt++) {
        f32x4 c = {0.f, 0.f, 0.f, 0.f};
        c = mfma16(a20, *(const bf16x8*)&wyc[ty][(nt * 16 + lid) * P64 + q * 8], c);
        c = mfma16(a21, *(const bf16x8*)&wyc[ty][(nt * 16 + lid) * P64 + 32 + q * 8], c);
        float by = bias_y[ty * 64 + nt * 16 + lid];
#pragma unroll
        for (int r = 0; r < 4; r++)
          y0[(size_t)idr_[r] * 128 + ty * 64 + nt * 16 + lid] = f2b(c[r] + by);
      }
    }

    // ---- f1 = feat @ W1_feat(own type) + b1(own type)
    bf16x8 af[2];
#pragma unroll
    for (int kt = 0; kt < 2; kt++) {
      const float4* p = (const float4*)(feat + (size_t)id * 64 + kt * 32 + q * 8);
      float4 xa = p[0], xb = p[1];
      bf16x8 f;
      f[0] = (__bf16)xa.x; f[1] = (__bf16)xa.y; f[2] = (__bf16)xa.z; f[3] = (__bf16)xa.w;
      f[4] = (__bf16)xb.x; f[5] = (__bf16)xb.y; f[6] = (__bf16)xb.z; f[7] = (__bf16)xb.w;
      af[kt] = f;
    }
#pragma unroll
    for (int nt = 0; nt < 4; nt++) {
      f32x4 cm = {0.f, 0.f, 0.f, 0.f}, cg = {0.f, 0.f, 0.f, 0.f};
#pragma unroll
      for (int kt = 0; kt < 2; kt++) {
        cm = mfma16(af[kt], *(const bf16x8*)&wf[0][(nt * 16 + lid) * P64 + kt * 32 + q * 8], cm);
        cg = mfma16(af[kt], *(const bf16x8*)&wf[1][(nt * 16 + lid) * P64 + kt * 32 + q * 8], cg);
      }
      float bm = nm_b1[nt * 16 + lid], bg = ng_b1[nt * 16 + lid];
#pragma unroll
      for (int r = 0; r < 4; r++) {
        int idr = idr_[r];
        bool mod = (mbits[idr >> 5] >> (idr & 31)) & 1;
        f1[(size_t)idr * 64 + nt * 16 + lid] = f2b(mod ? cm[r] + bm : cg[r] + bg);
      }
    }
  }
}

// ================= k_gather: mean via packed 4B slots (+spill) -> z1a ========
__global__ __launch_bounds__(256) void k_gather(const u16* y0, const int* rec,
                                                const u64* spill, const int* spillcnt,
                                                const u32* mbits, const u16* f1,
                                                const float* w_pos, u16* z1a, int N) {
  int n = (blockIdx.x * 256 + threadIdx.x) >> 6;
  int lane = threadIdx.x & 63;
  if (n >= N) return;
  bool mod = (mbits[n >> 5] >> (n & 31)) & 1;
  int sub = lane >> 5, l32 = lane & 31;
  // lanes 0..17 hold the record header+slots
  int rv = (lane < 18) ? rec[(size_t)n * RSTRIDE + lane] : 0;
  int cnt = __shfl(rv, 0);
  float pspill = __builtin_bit_cast(float, __shfl(rv, 1));
  int inl = cnt < CAP ? cnt : CAP;
  // in-slot bitpos sum: lane 2+j holds slot j -> 12-bit fixed-point pos
  float myb = 0.f;
  if (mod && lane >= 2 && lane < 18 && (lane - 2) < inl)
    myb = (float)(rv & 4095) * (1.f / 4096.f);
  const u32* yrow = (const u32*)y0;  // 64 u32 per node row
  int halfo = mod ? 0 : 32;
  float a0 = 0.f, a1 = 0.f;
  for (int j = 0; j < inl; j += 2) {
    int e2 = j + sub;
    if (e2 < inl) {
      int s = (int)(((u32)__shfl(rv, 2 + e2)) >> 12);  // src of slot e2
      u32 pk = yrow[(size_t)s * 64 + halfo + l32];
      a0 += b2f_lo(pk);
      a1 += b2f_hi(pk);
    }
  }
  if (cnt > CAP) {  // rare: scan spill list
    int sc = *spillcnt;
    for (int base = 0; base < sc; base += 64) {
      int i = base + lane;
      u64 ent = (i < sc) ? spill[i] : 0xffffffffffffffffull;
      bool m = ((int)(ent >> 32) == n);
      u64 bal = __ballot(m);
      int slo = (int)(ent & 0xffffffffu);
      while (bal) {
        int l = __ffsll((long long)bal) - 1;
        bal &= bal - 1;
        int s = __shfl(slo, l);
        if (sub == 0) {
          u32 pk = yrow[(size_t)s * 64 + halfo + l32];
          a0 += b2f_lo(pk);
          a1 += b2f_hi(pk);
        }
      }
    }
  }
  a0 += __shfl_xor(a0, 32);
  a1 += __shfl_xor(a1, 32);
#pragma unroll
  for (int off = 1; off < 64; off <<= 1) myb += __shfl_xor(myb, off);
  float psum = pspill + myb;
  float inv = 1.f / (float)(cnt > 1 ? cnt : 1);
  if (sub == 0) {
    u32 fp = ((const u32*)f1)[(size_t)n * 32 + l32];
    float z0 = a0 * inv + b2f_lo(fp);
    float z1v = a1 * inv + b2f_hi(fp);
    if (mod) {
      float pm = psum * inv;
      float2 wp = ((const float2*)w_pos)[l32];
      z0 += pm * wp.x;
      z1v += pm * wp.y;
    }
    ((u32*)z1a)[(size_t)n * 32 + l32] = (u32)f2b(leaky(z0)) | ((u32)f2b(leaky(z1v)) << 16);
  }
}

// ====== k_tail (persistent, fused): layer2 + select + relu + readout =========
__global__ __launch_bounds__(512) void k_tail(const u16* z1a, const u16* wt2m_g,
                                              const u16* wt2g_g, const float* nm_b2,
                                              const float* ng_b2, const u32* mbits,
                                              const int* is_po, const float* level,
                                              const float* g_w1, const float* g_b1,
                                              const u16* wt_oh_g, const u16* gt_g,
                                              const float* bp_g, const float* o_w2,
                                              const float* o_b2, float* out, int N) {
  __shared__ __align__(16) u16 w2[2][128 * P64];
  __shared__ __align__(16) u16 wt_oh[128 * P128];
  __shared__ __align__(16) u16 gt[128 * P64];
  __shared__ __align__(16) u16 tbuf[8][16 * P128];
  for (int i = threadIdx.x; i < 128 * P64 / 2; i += 512) {
    ((u32*)w2[0])[i] = ((const u32*)wt2m_g)[i];
    ((u32*)w2[1])[i] = ((const u32*)wt2g_g)[i];
    ((u32*)gt)[i] = ((const u32*)gt_g)[i];
  }
  for (int i = threadIdx.x; i < 128 * P128 / 2; i += 512)
    ((u32*)wt_oh)[i] = ((const u32*)wt_oh_g)[i];

  int lane = threadIdx.x & 63, wv = threadIdx.x >> 6;
  int lid = lane & 15, q = lane >> 4;
  int nbat = (N + 15) >> 4;

  float gw[2][8], gb[2][8];
#pragma unroll
  for (int kt = 0; kt < 2; kt++)
#pragma unroll
    for (int j = 0; j < 8; j++) {
      int k = kt * 32 + q * 8 + j;
      gw[kt][j] = g_w1[k];
      gb[kt][j] = g_b1[k];
    }
  float w2o[8], bpv[8];
#pragma unroll
  for (int nt = 0; nt < 8; nt++) {
    w2o[nt] = o_w2[nt * 16 + lid];
    bpv[nt] = bp_g[nt * 16 + lid];
  }
  float b2m[8], b2g[8];
#pragma unroll
  for (int nt = 0; nt < 8; nt++) {
    b2m[nt] = nm_b2[nt * 16 + lid];
    b2g[nt] = ng_b2[nt * 16 + lid];
  }
  float ob2 = o_b2[0];
  __syncthreads();  // weight LDS ready

  for (int b0 = blockIdx.x * 8; b0 < nbat; b0 += gridDim.x * 8) {
    int b = b0 + wv;
    int batch = b < nbat ? b : nbat - 1;
    int id = batch * 16 + lid;
    if (id >= N) id = N - 1;

    // ---- phase 1: layer-2 both types, select, relu -> tbuf (C-layout write)
    bf16x8 a0 = *(const bf16x8*)(z1a + (size_t)id * 64 + q * 8);
    bf16x8 a1 = *(const bf16x8*)(z1a + (size_t)id * 64 + 32 + q * 8);
    bool mod_[4], kp_[4];
#pragma unroll
    for (int r = 0; r < 4; r++) {
      int ii = batch * 16 + q * 4 + r;
      if (ii >= N) ii = N - 1;
      mod_[r] = (mbits[ii >> 5] >> (ii & 31)) & 1;
      kp_[r] = (is_po[ii] != 1);
    }
    __syncthreads();  // tbuf free (prev iter's reads done)
#pragma unroll
    for (int nt = 0; nt < 8; nt++) {
      f32x4 cm = {0.f, 0.f, 0.f, 0.f}, cg = {0.f, 0.f, 0.f, 0.f};
      cm = mfma16(a0, *(const bf16x8*)&w2[0][(nt * 16 + lid) * P64 + q * 8], cm);
      cm = mfma16(a1, *(const bf16x8*)&w2[0][(nt * 16 + lid) * P64 + 32 + q * 8], cm);
      cg = mfma16(a0, *(const bf16x8*)&w2[1][(nt * 16 + lid) * P64 + q * 8], cg);
      cg = mfma16(a1, *(const bf16x8*)&w2[1][(nt * 16 + lid) * P64 + 32 + q * 8], cg);
#pragma unroll
      for (int r = 0; r < 4; r++) {
        float v = mod_[r] ? cm[r] + b2m[nt] : cg[r] + b2g[nt];
        if (kp_[r]) v = fmaxf(v, 0.f);
        tbuf[wv][(q * 4 + r) * P128 + nt * 16 + lid] = f2b(v);
      }
    }
    __syncthreads();  // tbuf transpose visible

    // ---- phase 2: readout (h A-frags from tbuf + global branch)
    bf16x8 ah[4];
#pragma unroll
    for (int kt = 0; kt < 4; kt++)
      ah[kt] = *(const bf16x8*)&tbuf[wv][lid * P128 + kt * 32 + q * 8];
    float lv = level[id];
    bf16x8 ag[2];
#pragma unroll
    for (int kt = 0; kt < 2; kt++)
#pragma unroll
      for (int j = 0; j < 8; j++)
        ag[kt][j] = (__bf16)leaky(lv * gw[kt][j] + gb[kt][j]);

    f32x4 accv[8];
#pragma unroll
    for (int nt = 0; nt < 8; nt++) {
      f32x4 c = {0.f, 0.f, 0.f, 0.f};
#pragma unroll
      for (int kt = 0; kt < 4; kt++)
        c = mfma16(ah[kt], *(const bf16x8*)&wt_oh[(nt * 16 + lid) * P128 + kt * 32 + q * 8], c);
#pragma unroll
      for (int kt = 0; kt < 2; kt++)
        c = mfma16(ag[kt], *(const bf16x8*)&gt[(nt * 16 + lid) * P64 + kt * 32 + q * 8], c);
      accv[nt] = c;
    }
    float p[4];
#pragma unroll
    for (int r = 0; r < 4; r++) {
      float s = 0.f;
#pragma unroll
      for (int nt = 0; nt < 8; nt++) s += leaky(accv[nt][r] + bpv[nt]) * w2o[nt];
      p[r] = s;
    }
#pragma unroll
    for (int r = 0; r < 4; r++)
#pragma unroll
      for (int off = 1; off < 16; off <<= 1) p[r] += __shfl_xor(p[r], off, 16);
    if (lid == 0) {
#pragma unroll
      for (int r = 0; r < 4; r++) {
        int idr = batch * 16 + q * 4 + r;
        if (idr >= N) idr = N - 1;
        out[idr] = p[r] + ob2;
      }
    }
  }
}

extern "C" void kernel_launch(void* const* d_in, const int* in_sizes, int n_in,
                              void* d_out, int out_size, void* d_ws, size_t ws_size,
                              hipStream_t stream) {
  const float* feat = (const float*)d_in[0];
  const float* pi_feat = (const float*)d_in[1];
  const float* level = (const float*)d_in[2];
  const float* bitpos = (const float*)d_in[3];
  const int* is_po = (const int*)d_in[4];
  const int* is_module = (const int*)d_in[5];
  const int* src_m = (const int*)d_in[6];
  const int* dst_m = (const int*)d_in[7];
  const int* src_g = (const int*)d_in[8];
  const int* dst_g = (const int*)d_in[9];
  const float* pi_w1 = (const float*)d_in[10];
  const float* pi_b1 = (const float*)d_in[11];
  const float* pi_w2 = (const float*)d_in[12];
  const float* pi_b2 = (const float*)d_in[13];
  const float* nm_w1 = (const float*)d_in[14];
  const float* nm_b1 = (const float*)d_in[15];
  const float* nm_w2 = (const float*)d_in[16];
  const float* nm_b2 = (const float*)d_in[17];
  const float* ng_w1 = (const float*)d_in[18];
  const float* ng_b1 = (const float*)d_in[19];
  const float* ng_w2 = (const float*)d_in[20];
  const float* ng_b2 = (const float*)d_in[21];
  const float* g_w1 = (const float*)d_in[22];
  const float* g_b1 = (const float*)d_in[23];
  const float* g_w2 = (const float*)d_in[24];
  const float* g_b2 = (const float*)d_in[25];
  const float* o_w1 = (const float*)d_in[26];
  const float* o_b1 = (const float*)d_in[27];
  const float* o_w2 = (const float*)d_in[28];
  const float* o_b2 = (const float*)d_in[29];

  int N = in_sizes[0] / 64;
  int E = in_sizes[3];

  char* ws = (char*)d_ws;
  size_t off = 0;
  auto alloc = [&](size_t bytes) {
    char* p = ws + off;
    off += (bytes + 255) & ~(size_t)255;
    return p;
  };
  int* rec = (int*)alloc(((size_t)N * RSTRIDE + 64) * 4);
  int* spillcnt = (int*)alloc(16);
  u64* spill = (u64*)alloc((size_t)2 * E * 8);
  u32* mbits = (u32*)alloc((size_t)((N + 31) / 32) * 4);
  u16* y0 = (u16*)alloc((size_t)N * 128 * 2);
  u16* f1 = (u16*)alloc((size_t)N * 64 * 2);
  u16* z1a = (u16*)alloc((size_t)N * 64 * 2);
  u16* wt_yc = (u16*)alloc(9216 * 2);
  float* bias_y = (float*)alloc(128 * 4);
  u16* wt_f1m = (u16*)alloc(4608 * 2);
  u16* wt_f1g = (u16*)alloc(4608 * 2);
  float* w_pos = (float*)alloc(64 * 4);
  u16* wt2m = (u16*)alloc(9216 * 2);
  u16* wt2g = (u16*)alloc(9216 * 2);
  u16* wt_oh = (u16*)alloc(17408 * 2);
  u16* gt = (u16*)alloc(9216 * 2);
  float* bp = (float*)alloc(128 * 4);

  // 1. weight prep + mbits + record-header zeroing (no separate memset)
  int prep_items = 63808 + ((N + 63) & ~63);
  k_prep<<<(prep_items + 255) / 256, 256, 0, stream>>>(
      nm_w1, ng_w1, nm_w2, ng_w2, o_w1, o_b1, g_w2, g_b2, pi_w2, pi_b2, is_module,
      wt_yc, bias_y, wt_f1m, wt_f1g, w_pos, wt2m, wt2g, wt_oh, gt, bp, mbits,
      rec, spillcnt, N);

  // 2. single edge pass into 128B records (nt loads/stores)
  k_scatter<<<(2 * E + 255) / 256, 256, 0, stream>>>(src_m, dst_m, src_g, dst_g,
                                                     mbits, bitpos, rec, spill,
                                                     spillcnt, E);

  // 3. node precompute (persistent)
  k_pre<<<512, 512, 0, stream>>>(
      pi_feat, feat, pi_w1, pi_b1, wt_yc, bias_y, wt_f1m, wt_f1g,
      nm_b1, ng_b1, mbits, y0, f1, N);

  // 4. gather + layer-1 finalize
  k_gather<<<(N * 64 + 255) / 256, 256, 0, stream>>>(
      y0, rec, spill, spillcnt, mbits, f1, w_pos, z1a, N);

  // 5. fused tail: layer-2 + select + relu + readout (persistent, h in regs)
  k_tail<<<256, 512, 0, stream>>>(z1a, wt2m, wt2g, nm_b2, ng_b2, mbits, is_po,
                                  level, g_w1, g_b1, wt_oh, gt, bp, o_w2, o_b2,
                                  (float*)d_out, N);
}

// Round 13
// 273.941 us; speedup vs baseline: 1.0693x; 1.0693x over previous
//
#include <hip/hip_runtime.h>

typedef __bf16 bf16x8 __attribute__((ext_vector_type(8)));
typedef float f32x4 __attribute__((ext_vector_type(4)));
typedef unsigned short u16;
typedef unsigned int u32;
typedef unsigned long long u64;

__device__ __forceinline__ u16 f2b(float f) {
  return __builtin_bit_cast(u16, (__bf16)f);
}
__device__ __forceinline__ float b2f_lo(u32 pk) {
  return __builtin_bit_cast(float, pk << 16);
}
__device__ __forceinline__ float b2f_hi(u32 pk) {
  return __builtin_bit_cast(float, pk & 0xffff0000u);
}
__device__ __forceinline__ float leaky(float x) { return x > 0.f ? x : 0.1f * x; }
__device__ __forceinline__ f32x4 mfma16(bf16x8 a, bf16x8 b, f32x4 c) {
  return __builtin_amdgcn_mfma_f32_16x16x32_bf16(a, b, c, 0, 0, 0);
}

// LDS row paddings: 64->72, 128->136 u16 (stride%32 dwords = 4 -> 2-way, free)
#define P64 72
#define P128 136
// fixed-stride CSR record, 128B (2 cache lines), 32 ints:
//   int[0]=cnt  int[1]=pspill(float, spill-only possum)
//   int[2+j] = slot j = (src<<12) | fix12(bitpos)   (src < 2^20, 12-bit pos)
#define CAP 16
#define RSTRIDE 32  // ints

// ================= k_prep: weight transposes (PADDED layouts) + mbits ========
__global__ __launch_bounds__(256) void k_prep(
    const float* nm_w1, const float* ng_w1, const float* nm_w2, const float* ng_w2,
    const float* o_w1, const float* o_b1, const float* g_w2, const float* g_b2,
    const float* pi_w2, const float* pi_b2, const int* is_module,
    u16* wt_yc, float* bias_y, u16* wt_f1m, u16* wt_f1g, float* w_pos,
    u16* wt2m, u16* wt2g, u16* wt_oh, u16* gt, float* bp, u32* mbits, int N) {
  int i = blockIdx.x * 256 + threadIdx.x;
  if (i < 9216) {
    int ty = i / 4608, rem = i % 4608, n = rem / P64, k = rem % P64;
    float v = 0.f;
    if (k < 64) {
      const float* w1 = ty ? ng_w1 : nm_w1;
      for (int t = 0; t < 128; t++) v += pi_w2[k * 128 + t] * w1[t * 64 + n];
    }
    wt_yc[i] = f2b(v);
    return;
  }
  i -= 9216;
  if (i < 128) {
    int ty = i >> 6, n = i & 63;
    const float* w1 = ty ? ng_w1 : nm_w1;
    float v = 0.f;
    for (int t = 0; t < 128; t++) v += pi_b2[t] * w1[t * 64 + n];
    bias_y[i] = v;
    return;
  }
  i -= 128;
  if (i < 4608) {
    int n = i / P64, k = i % P64;
    wt_f1m[i] = f2b(k < 64 ? nm_w1[(129 + k) * 64 + n] : 0.f);
    return;
  }
  i -= 4608;
  if (i < 4608) {
    int n = i / P64, k = i % P64;
    wt_f1g[i] = f2b(k < 64 ? ng_w1[(128 + k) * 64 + n] : 0.f);
    return;
  }
  i -= 4608;
  if (i < 64) { w_pos[i] = nm_w1[128 * 64 + i]; return; }
  i -= 64;
  if (i < 9216) {
    int n = i / P64, k = i % P64;
    wt2m[i] = f2b(k < 64 ? nm_w2[k * 128 + n] : 0.f);
    return;
  }
  i -= 9216;
  if (i < 9216) {
    int n = i / P64, k = i % P64;
    wt2g[i] = f2b(k < 64 ? ng_w2[k * 128 + n] : 0.f);
    return;
  }
  i -= 9216;
  if (i < 17408) {
    int n = i / P128, k = i % P128;
    wt_oh[i] = f2b(k < 128 ? o_w1[k * 128 + n] : 0.f);
    return;
  }
  i -= 17408;
  if (i < 9216) {
    int n = i / P64, k = i % P64;
    float v = 0.f;
    if (k < 64)
      for (int t = 0; t < 128; t++) v += g_w2[k * 128 + t] * o_w1[(128 + t) * 128 + n];
    gt[i] = f2b(v);
    return;
  }
  i -= 9216;
  if (i < 128) {
    float s = o_b1[i];
    for (int t = 0; t < 128; t++) s += g_b2[t] * o_w1[(128 + t) * 128 + i];
    bp[i] = s;
    return;
  }
  i -= 128;
  // mbits ballot segment (wave-aligned: 63808 % 64 == 0)
  {
    int n = i;
    int lane = threadIdx.x & 63;
    bool v = (n < N) && (is_module[n] == 1);
    u64 b = __ballot(v);
    if (lane == 0 && n < N) mbits[n >> 5] = (u32)b;
    if (lane == 32 && n < N) mbits[n >> 5] = (u32)(b >> 32);
  }
}

// ================= k_scatter: 2 edges/thread (double outstanding atomics) ====
__global__ void k_scatter(const int* src_m, const int* dst_m, const int* src_g,
                          const int* dst_g, const u32* mbits, const float* bitpos,
                          int* rec, u64* spill, int* spillcnt, int E) {
  int e0 = (blockIdx.x * 256 + threadIdx.x) * 2;
#pragma unroll
  for (int j = 0; j < 2; j++) {
    int e = e0 + j;
    if (e < E) {
      int d = dst_m[e];
      if ((mbits[d >> 5] >> (d & 31)) & 1) {
        int c = atomicAdd(&rec[d * RSTRIDE], 1);
        int s = src_m[e];
        float bpv = bitpos[e];
        if (c < CAP) {
          int bp12 = (int)(bpv * 4096.f);
          if (bp12 > 4095) bp12 = 4095;
          rec[(size_t)d * RSTRIDE + 2 + c] = (s << 12) | bp12;
        } else {
          int p = atomicAdd(spillcnt, 1);
          spill[p] = ((u64)(u32)d << 32) | (u32)s;
          atomicAdd((float*)&rec[d * RSTRIDE + 1], bpv);
        }
      }
    } else if (e < 2 * E) {
      int d = dst_g[e - E];
      if (!((mbits[d >> 5] >> (d & 31)) & 1)) {
        int c = atomicAdd(&rec[d * RSTRIDE], 1);
        int s = src_g[e - E];
        if (c < CAP) {
          rec[(size_t)d * RSTRIDE + 2 + c] = s << 12;
        } else {
          int p = atomicAdd(spillcnt, 1);
          spill[p] = ((u64)(u32)d << 32) | (u32)s;
        }
      }
    }
  }
}

// ================= k_pre (persistent): layer1(pi) -> y0 ; f1 =================
__global__ __launch_bounds__(512) void k_pre(const float* pf, const float* feat,
                                             const float* pi_w1, const float* pi_b1,
                                             const u16* wt_yc_g, const float* bias_y,
                                             const u16* wt_f1m_g, const u16* wt_f1g_g,
                                             const float* nm_b1, const float* ng_b1,
                                             const u32* mbits,
                                             u16* y0, u16* f1, int N) {
  __shared__ __align__(16) u16 wyc[2][64 * P64];
  __shared__ __align__(16) u16 wf[2][64 * P64];
  __shared__ __align__(16) u16 tbuf[8][16 * P64];
  for (int i = threadIdx.x; i < 2304; i += 512) {
    ((u32*)wyc[0])[i] = ((const u32*)wt_yc_g)[i];
    ((u32*)wyc[1])[i] = ((const u32*)wt_yc_g)[2304 + i];
    ((u32*)wf[0])[i] = ((const u32*)wt_f1m_g)[i];
    ((u32*)wf[1])[i] = ((const u32*)wt_f1g_g)[i];
  }

  int lane = threadIdx.x & 63, wv = threadIdx.x >> 6;
  int lid = lane & 15, q = lane >> 4;

  bf16x8 w1f[4];
#pragma unroll
  for (int nt = 0; nt < 4; nt++) {
    bf16x8 f;
#pragma unroll
    for (int j = 0; j < 8; j++) {
      int k = q * 8 + j;
      f[j] = (__bf16)((k < 4) ? pi_w1[k * 64 + nt * 16 + lid] : 0.f);
    }
    w1f[nt] = f;
  }
  __syncthreads();  // weight LDS ready

  int nbat = (N + 15) >> 4;
  for (int b0 = blockIdx.x * 8; b0 < nbat; b0 += gridDim.x * 8) {
    int b = b0 + wv;
    int batch = b < nbat ? b : nbat - 1;
    int id = batch * 16 + lid;
    if (id >= N) id = N - 1;

    // ---- pi layer 1: 4 -> 64, leaky -> tbuf (A-layout transpose)
    bf16x8 a;
#pragma unroll
    for (int j = 0; j < 8; j++)
      a[j] = (__bf16)((q == 0 && j < 4) ? pf[(size_t)id * 4 + j] : 0.f);
    f32x4 z1[4];
#pragma unroll
    for (int nt = 0; nt < 4; nt++) {
      f32x4 c = {0.f, 0.f, 0.f, 0.f};
      z1[nt] = mfma16(a, w1f[nt], c);
    }
    __syncthreads();
#pragma unroll
    for (int nt = 0; nt < 4; nt++) {
      float bb = pi_b1[nt * 16 + lid];
#pragma unroll
      for (int r = 0; r < 4; r++)
        tbuf[wv][(q * 4 + r) * P64 + nt * 16 + lid] = f2b(leaky(z1[nt][r] + bb));
    }
    __syncthreads();
    bf16x8 a20 = *(const bf16x8*)&tbuf[wv][lid * P64 + q * 8];
    bf16x8 a21 = *(const bf16x8*)&tbuf[wv][lid * P64 + 32 + q * 8];

    int idr_[4];
#pragma unroll
    for (int r = 0; r < 4; r++) {
      int ii = batch * 16 + q * 4 + r;
      idr_[r] = ii < N ? ii : N - 1;
    }

    // ---- y0[ty] = a2 @ Wcomb_ty + bias_y_ty (64 -> 64 per type)
#pragma unroll
    for (int ty = 0; ty < 2; ty++) {
#pragma unroll
      for (int nt = 0; nt < 4; nt++) {
        f32x4 c = {0.f, 0.f, 0.f, 0.f};
        c = mfma16(a20, *(const bf16x8*)&wyc[ty][(nt * 16 + lid) * P64 + q * 8], c);
        c = mfma16(a21, *(const bf16x8*)&wyc[ty][(nt * 16 + lid) * P64 + 32 + q * 8], c);
        float by = bias_y[ty * 64 + nt * 16 + lid];
#pragma unroll
        for (int r = 0; r < 4; r++)
          y0[(size_t)idr_[r] * 128 + ty * 64 + nt * 16 + lid] = f2b(c[r] + by);
      }
    }

    // ---- f1 = feat @ W1_feat(own type) + b1(own type)
    bf16x8 af[2];
#pragma unroll
    for (int kt = 0; kt < 2; kt++) {
      const float4* p = (const float4*)(feat + (size_t)id * 64 + kt * 32 + q * 8);
      float4 xa = p[0], xb = p[1];
      bf16x8 f;
      f[0] = (__bf16)xa.x; f[1] = (__bf16)xa.y; f[2] = (__bf16)xa.z; f[3] = (__bf16)xa.w;
      f[4] = (__bf16)xb.x; f[5] = (__bf16)xb.y; f[6] = (__bf16)xb.z; f[7] = (__bf16)xb.w;
      af[kt] = f;
    }
#pragma unroll
    for (int nt = 0; nt < 4; nt++) {
      f32x4 cm = {0.f, 0.f, 0.f, 0.f}, cg = {0.f, 0.f, 0.f, 0.f};
#pragma unroll
      for (int kt = 0; kt < 2; kt++) {
        cm = mfma16(af[kt], *(const bf16x8*)&wf[0][(nt * 16 + lid) * P64 + kt * 32 + q * 8], cm);
        cg = mfma16(af[kt], *(const bf16x8*)&wf[1][(nt * 16 + lid) * P64 + kt * 32 + q * 8], cg);
      }
      float bm = nm_b1[nt * 16 + lid], bg = ng_b1[nt * 16 + lid];
#pragma unroll
      for (int r = 0; r < 4; r++) {
        int idr = idr_[r];
        bool mod = (mbits[idr >> 5] >> (idr & 31)) & 1;
        f1[(size_t)idr * 64 + nt * 16 + lid] = f2b(mod ? cm[r] + bm : cg[r] + bg);
      }
    }
  }
}

// ================= k_gather: mean via packed 4B slots (+spill) -> z1a ========
__global__ __launch_bounds__(256) void k_gather(const u16* y0, const int* rec,
                                                const u64* spill, const int* spillcnt,
                                                const u32* mbits, const u16* f1,
                                                const float* w_pos, u16* z1a, int N) {
  int n = (blockIdx.x * 256 + threadIdx.x) >> 6;
  int lane = threadIdx.x & 63;
  if (n >= N) return;
  bool mod = (mbits[n >> 5] >> (n & 31)) & 1;
  int sub = lane >> 5, l32 = lane & 31;
  // lanes 0..17 hold the record header+slots
  int rv = (lane < 18) ? rec[(size_t)n * RSTRIDE + lane] : 0;
  int cnt = __shfl(rv, 0);
  float pspill = __builtin_bit_cast(float, __shfl(rv, 1));
  int inl = cnt < CAP ? cnt : CAP;
  // in-slot bitpos sum: lane 2+j holds slot j -> 12-bit fixed-point pos
  float myb = 0.f;
  if (mod && lane >= 2 && lane < 18 && (lane - 2) < inl)
    myb = (float)(rv & 4095) * (1.f / 4096.f);
  const u32* yrow = (const u32*)y0;  // 64 u32 per node row
  int halfo = mod ? 0 : 32;
  float a0 = 0.f, a1 = 0.f;
  for (int j = 0; j < inl; j += 2) {
    int e2 = j + sub;
    if (e2 < inl) {
      int s = (int)(((u32)__shfl(rv, 2 + e2)) >> 12);  // src of slot e2
      u32 pk = yrow[(size_t)s * 64 + halfo + l32];
      a0 += b2f_lo(pk);
      a1 += b2f_hi(pk);
    }
  }
  if (cnt > CAP) {  // rare: scan spill list
    int sc = *spillcnt;
    for (int base = 0; base < sc; base += 64) {
      int i = base + lane;
      u64 ent = (i < sc) ? spill[i] : 0xffffffffffffffffull;
      bool m = ((int)(ent >> 32) == n);
      u64 bal = __ballot(m);
      int slo = (int)(ent & 0xffffffffu);
      while (bal) {
        int l = __ffsll((long long)bal) - 1;
        bal &= bal - 1;
        int s = __shfl(slo, l);
        if (sub == 0) {
          u32 pk = yrow[(size_t)s * 64 + halfo + l32];
          a0 += b2f_lo(pk);
          a1 += b2f_hi(pk);
        }
      }
    }
  }
  a0 += __shfl_xor(a0, 32);
  a1 += __shfl_xor(a1, 32);
#pragma unroll
  for (int off = 1; off < 64; off <<= 1) myb += __shfl_xor(myb, off);
  float psum = pspill + myb;
  float inv = 1.f / (float)(cnt > 1 ? cnt : 1);
  if (sub == 0) {
    u32 fp = ((const u32*)f1)[(size_t)n * 32 + l32];
    float z0 = a0 * inv + b2f_lo(fp);
    float z1v = a1 * inv + b2f_hi(fp);
    if (mod) {
      float pm = psum * inv;
      float2 wp = ((const float2*)w_pos)[l32];
      z0 += pm * wp.x;
      z1v += pm * wp.y;
    }
    ((u32*)z1a)[(size_t)n * 32 + l32] = (u32)f2b(leaky(z0)) | ((u32)f2b(leaky(z1v)) << 16);
  }
}

// ====== k_tail (persistent, fused): layer2 + select + relu + readout =========
__global__ __launch_bounds__(512) void k_tail(const u16* z1a, const u16* wt2m_g,
                                              const u16* wt2g_g, const float* nm_b2,
                                              const float* ng_b2, const u32* mbits,
                                              const int* is_po, const float* level,
                                              const float* g_w1, const float* g_b1,
                                              const u16* wt_oh_g, const u16* gt_g,
                                              const float* bp_g, const float* o_w2,
                                              const float* o_b2, float* out, int N) {
  __shared__ __align__(16) u16 w2[2][128 * P64];
  __shared__ __align__(16) u16 wt_oh[128 * P128];
  __shared__ __align__(16) u16 gt[128 * P64];
  __shared__ __align__(16) u16 tbuf[8][16 * P128];
  for (int i = threadIdx.x; i < 128 * P64 / 2; i += 512) {
    ((u32*)w2[0])[i] = ((const u32*)wt2m_g)[i];
    ((u32*)w2[1])[i] = ((const u32*)wt2g_g)[i];
    ((u32*)gt)[i] = ((const u32*)gt_g)[i];
  }
  for (int i = threadIdx.x; i < 128 * P128 / 2; i += 512)
    ((u32*)wt_oh)[i] = ((const u32*)wt_oh_g)[i];

  int lane = threadIdx.x & 63, wv = threadIdx.x >> 6;
  int lid = lane & 15, q = lane >> 4;
  int nbat = (N + 15) >> 4;

  float gw[2][8], gb[2][8];
#pragma unroll
  for (int kt = 0; kt < 2; kt++)
#pragma unroll
    for (int j = 0; j < 8; j++) {
      int k = kt * 32 + q * 8 + j;
      gw[kt][j] = g_w1[k];
      gb[kt][j] = g_b1[k];
    }
  float w2o[8], bpv[8];
#pragma unroll
  for (int nt = 0; nt < 8; nt++) {
    w2o[nt] = o_w2[nt * 16 + lid];
    bpv[nt] = bp_g[nt * 16 + lid];
  }
  float b2m[8], b2g[8];
#pragma unroll
  for (int nt = 0; nt < 8; nt++) {
    b2m[nt] = nm_b2[nt * 16 + lid];
    b2g[nt] = ng_b2[nt * 16 + lid];
  }
  float ob2 = o_b2[0];
  __syncthreads();  // weight LDS ready

  for (int b0 = blockIdx.x * 8; b0 < nbat; b0 += gridDim.x * 8) {
    int b = b0 + wv;
    int batch = b < nbat ? b : nbat - 1;
    int id = batch * 16 + lid;
    if (id >= N) id = N - 1;

    // ---- phase 1: layer-2 both types, select, relu -> tbuf (C-layout write)
    bf16x8 a0 = *(const bf16x8*)(z1a + (size_t)id * 64 + q * 8);
    bf16x8 a1 = *(const bf16x8*)(z1a + (size_t)id * 64 + 32 + q * 8);
    bool mod_[4], kp_[4];
#pragma unroll
    for (int r = 0; r < 4; r++) {
      int ii = batch * 16 + q * 4 + r;
      if (ii >= N) ii = N - 1;
      mod_[r] = (mbits[ii >> 5] >> (ii & 31)) & 1;
      kp_[r] = (is_po[ii] != 1);
    }
    __syncthreads();  // tbuf free (prev iter's reads done)
#pragma unroll
    for (int nt = 0; nt < 8; nt++) {
      f32x4 cm = {0.f, 0.f, 0.f, 0.f}, cg = {0.f, 0.f, 0.f, 0.f};
      cm = mfma16(a0, *(const bf16x8*)&w2[0][(nt * 16 + lid) * P64 + q * 8], cm);
      cm = mfma16(a1, *(const bf16x8*)&w2[0][(nt * 16 + lid) * P64 + 32 + q * 8], cm);
      cg = mfma16(a0, *(const bf16x8*)&w2[1][(nt * 16 + lid) * P64 + q * 8], cg);
      cg = mfma16(a1, *(const bf16x8*)&w2[1][(nt * 16 + lid) * P64 + 32 + q * 8], cg);
#pragma unroll
      for (int r = 0; r < 4; r++) {
        float v = mod_[r] ? cm[r] + b2m[nt] : cg[r] + b2g[nt];
        if (kp_[r]) v = fmaxf(v, 0.f);
        tbuf[wv][(q * 4 + r) * P128 + nt * 16 + lid] = f2b(v);
      }
    }
    __syncthreads();  // tbuf transpose visible

    // ---- phase 2: readout (h A-frags from tbuf + global branch)
    bf16x8 ah[4];
#pragma unroll
    for (int kt = 0; kt < 4; kt++)
      ah[kt] = *(const bf16x8*)&tbuf[wv][lid * P128 + kt * 32 + q * 8];
    float lv = level[id];
    bf16x8 ag[2];
#pragma unroll
    for (int kt = 0; kt < 2; kt++)
#pragma unroll
      for (int j = 0; j < 8; j++)
        ag[kt][j] = (__bf16)leaky(lv * gw[kt][j] + gb[kt][j]);

    f32x4 accv[8];
#pragma unroll
    for (int nt = 0; nt < 8; nt++) {
      f32x4 c = {0.f, 0.f, 0.f, 0.f};
#pragma unroll
      for (int kt = 0; kt < 4; kt++)
        c = mfma16(ah[kt], *(const bf16x8*)&wt_oh[(nt * 16 + lid) * P128 + kt * 32 + q * 8], c);
#pragma unroll
      for (int kt = 0; kt < 2; kt++)
        c = mfma16(ag[kt], *(const bf16x8*)&gt[(nt * 16 + lid) * P64 + kt * 32 + q * 8], c);
      accv[nt] = c;
    }
    float p[4];
#pragma unroll
    for (int r = 0; r < 4; r++) {
      float s = 0.f;
#pragma unroll
      for (int nt = 0; nt < 8; nt++) s += leaky(accv[nt][r] + bpv[nt]) * w2o[nt];
      p[r] = s;
    }
#pragma unroll
    for (int r = 0; r < 4; r++)
#pragma unroll
      for (int off = 1; off < 16; off <<= 1) p[r] += __shfl_xor(p[r], off, 16);
    if (lid == 0) {
#pragma unroll
      for (int r = 0; r < 4; r++) {
        int idr = batch * 16 + q * 4 + r;
        if (idr >= N) idr = N - 1;
        out[idr] = p[r] + ob2;
      }
    }
  }
}

extern "C" void kernel_launch(void* const* d_in, const int* in_sizes, int n_in,
                              void* d_out, int out_size, void* d_ws, size_t ws_size,
                              hipStream_t stream) {
  const float* feat = (const float*)d_in[0];
  const float* pi_feat = (const float*)d_in[1];
  const float* level = (const float*)d_in[2];
  const float* bitpos = (const float*)d_in[3];
  const int* is_po = (const int*)d_in[4];
  const int* is_module = (const int*)d_in[5];
  const int* src_m = (const int*)d_in[6];
  const int* dst_m = (const int*)d_in[7];
  const int* src_g = (const int*)d_in[8];
  const int* dst_g = (const int*)d_in[9];
  const float* pi_w1 = (const float*)d_in[10];
  const float* pi_b1 = (const float*)d_in[11];
  const float* pi_w2 = (const float*)d_in[12];
  const float* pi_b2 = (const float*)d_in[13];
  const float* nm_w1 = (const float*)d_in[14];
  const float* nm_b1 = (const float*)d_in[15];
  const float* nm_w2 = (const float*)d_in[16];
  const float* nm_b2 = (const float*)d_in[17];
  const float* ng_w1 = (const float*)d_in[18];
  const float* ng_b1 = (const float*)d_in[19];
  const float* ng_w2 = (const float*)d_in[20];
  const float* ng_b2 = (const float*)d_in[21];
  const float* g_w1 = (const float*)d_in[22];
  const float* g_b1 = (const float*)d_in[23];
  const float* g_w2 = (const float*)d_in[24];
  const float* g_b2 = (const float*)d_in[25];
  const float* o_w1 = (const float*)d_in[26];
  const float* o_b1 = (const float*)d_in[27];
  const float* o_w2 = (const float*)d_in[28];
  const float* o_b2 = (const float*)d_in[29];

  int N = in_sizes[0] / 64;
  int E = in_sizes[3];

  char* ws = (char*)d_ws;
  size_t off = 0;
  auto alloc = [&](size_t bytes) {
    char* p = ws + off;
    off += (bytes + 255) & ~(size_t)255;
    return p;
  };
  // zero-init region: records (cnt+pspill live inside) + spill counter
  int* rec = (int*)alloc(((size_t)N * RSTRIDE + 64) * 4);
  int* spillcnt = (int*)alloc(16);
  size_t zero_bytes = off;
  // scratch
  u64* spill = (u64*)alloc((size_t)2 * E * 8);
  u32* mbits = (u32*)alloc((size_t)((N + 31) / 32) * 4);
  u16* y0 = (u16*)alloc((size_t)N * 128 * 2);
  u16* f1 = (u16*)alloc((size_t)N * 64 * 2);
  u16* z1a = (u16*)alloc((size_t)N * 64 * 2);
  u16* wt_yc = (u16*)alloc(9216 * 2);
  float* bias_y = (float*)alloc(128 * 4);
  u16* wt_f1m = (u16*)alloc(4608 * 2);
  u16* wt_f1g = (u16*)alloc(4608 * 2);
  float* w_pos = (float*)alloc(64 * 4);
  u16* wt2m = (u16*)alloc(9216 * 2);
  u16* wt2g = (u16*)alloc(9216 * 2);
  u16* wt_oh = (u16*)alloc(17408 * 2);
  u16* gt = (u16*)alloc(9216 * 2);
  float* bp = (float*)alloc(128 * 4);

  hipMemsetAsync(rec, 0, zero_bytes, stream);

  // 1. weight prep + mbits
  int prep_items = 63808 + ((N + 63) & ~63);
  k_prep<<<(prep_items + 255) / 256, 256, 0, stream>>>(
      nm_w1, ng_w1, nm_w2, ng_w2, o_w1, o_b1, g_w2, g_b2, pi_w2, pi_b2, is_module,
      wt_yc, bias_y, wt_f1m, wt_f1g, w_pos, wt2m, wt2g, wt_oh, gt, bp, mbits, N);

  // 2. single edge pass into 128B records (2 edges/thread for atomic ILP)
  k_scatter<<<(2 * E + 511) / 512, 256, 0, stream>>>(src_m, dst_m, src_g, dst_g,
                                                     mbits, bitpos, rec, spill,
                                                     spillcnt, E);

  // 3. node precompute (persistent)
  k_pre<<<512, 512, 0, stream>>>(
      pi_feat, feat, pi_w1, pi_b1, wt_yc, bias_y, wt_f1m, wt_f1g,
      nm_b1, ng_b1, mbits, y0, f1, N);

  // 4. gather + layer-1 finalize
  k_gather<<<(N * 64 + 255) / 256, 256, 0, stream>>>(
      y0, rec, spill, spillcnt, mbits, f1, w_pos, z1a, N);

  // 5. fused tail: layer-2 + select + relu + readout (persistent, h in regs)
  k_tail<<<256, 512, 0, stream>>>(z1a, wt2m, wt2g, nm_b2, ng_b2, mbits, is_po,
                                  level, g_w1, g_b1, wt_oh, gt, bp, o_w2, o_b2,
                                  (float*)d_out, N);
}